// Round 1
// baseline (31.279 us; speedup 1.0000x reference)
//
#include <hip/hip_runtime.h>
#include <math.h>

#define IN_DIMS 128
#define OUT_PER_B (IN_DIMS * 9)

// Force a wave-uniform value into an SGPR so v_fma can use it as the scalar operand.
__device__ __forceinline__ float uload(const float* __restrict__ p) {
    float v = *p;
    return __int_as_float(__builtin_amdgcn_readfirstlane(__float_as_int(v)));
}

__global__ __launch_bounds__(128) void ese_kernel(
        const float* __restrict__ x,     // (B, 128, 8, 8)
        const float* __restrict__ emb,   // (9, 8, 8)
        float* __restrict__ out)         // (B, 1152)
{
    __shared__ float s_out[OUT_PER_B];
    __shared__ float s_red[2];

    const int b = blockIdx.x;
    const int i = threadIdx.x;           // channel 0..127

    // emb[3a+c][h][w] separates as sA[a][w] * sB[c][h] * const, where the
    // constant (emb[0][0][0] > 0) cancels in the final L2 normalization.
    float sA[3][8];
    float sB[3][8];
#pragma unroll
    for (int a = 0; a < 3; ++a)
#pragma unroll
        for (int w = 0; w < 8; ++w)
            sA[a][w] = uload(&emb[(3 * a) * 64 + w]);      // emb[3a][0][w]
#pragma unroll
    for (int c = 0; c < 3; ++c)
#pragma unroll
        for (int h = 0; h < 8; ++h)
            sB[c][h] = uload(&emb[c * 64 + h * 8]);        // emb[c][h][0]

    const float4* __restrict__ xr =
        reinterpret_cast<const float4*>(x + ((size_t)b * IN_DIMS + i) * 64);

    float acc[9];
#pragma unroll
    for (int j = 0; j < 9; ++j) acc[j] = 0.0f;

#pragma unroll
    for (int h = 0; h < 8; ++h) {
        const float4 xa = xr[2 * h];
        const float4 xb = xr[2 * h + 1];
        float u[3];
#pragma unroll
        for (int a = 0; a < 3; ++a) {
            u[a] = xa.x * sA[a][0] + xa.y * sA[a][1]
                 + xa.z * sA[a][2] + xa.w * sA[a][3]
                 + xb.x * sA[a][4] + xb.y * sA[a][5]
                 + xb.z * sA[a][6] + xb.w * sA[a][7];
        }
#pragma unroll
        for (int a = 0; a < 3; ++a)
#pragma unroll
            for (int c = 0; c < 3; ++c)
                acc[3 * a + c] += u[a] * sB[c][h];
    }

    // Per-b L2 norm over all 128*9 outputs: per-thread ss -> wave reduce -> LDS.
    float ss = 0.0f;
#pragma unroll
    for (int j = 0; j < 9; ++j) ss += acc[j] * acc[j];
#pragma unroll
    for (int off = 32; off > 0; off >>= 1)
        ss += __shfl_xor(ss, off, 64);
    if ((i & 63) == 0) s_red[i >> 6] = ss;
    __syncthreads();
    const float total = s_red[0] + s_red[1];
    const float rn = 1.0f / sqrtf(total + 1e-10f);

    // Stage scaled outputs in LDS (stride 9 is coprime to 32 banks -> conflict-free),
    // then store coalesced.
#pragma unroll
    for (int j = 0; j < 9; ++j) s_out[i * 9 + j] = acc[j] * rn;
    __syncthreads();

    float* __restrict__ ob = out + (size_t)b * OUT_PER_B;
#pragma unroll
    for (int k = 0; k < 9; ++k)
        ob[k * IN_DIMS + i] = s_out[k * IN_DIMS + i];
}

extern "C" void kernel_launch(void* const* d_in, const int* in_sizes, int n_in,
                              void* d_out, int out_size, void* d_ws, size_t ws_size,
                              hipStream_t stream) {
    const float* x   = (const float*)d_in[0];
    const float* emb = (const float*)d_in[1];
    float* out       = (float*)d_out;

    const int B = in_sizes[0] / (IN_DIMS * 64);   // 4096
    ese_kernel<<<B, IN_DIMS, 0, stream>>>(x, emb, out);
}

// Round 2
// 27.919 us; speedup vs baseline: 1.1204x; 1.1204x over previous
//
#include <hip/hip_runtime.h>
#include <math.h>

#define IN_DIMS 128
#define OUT_PER_B (IN_DIMS * 9)

// Block = 512 threads = one batch element.
// Lane decomposition: c = t>>2 (channel), s = t&3 (quarter of the 256-B channel row).
// Load k (k=0..3): float4 at byte offset 16*s + 64*k of channel c.
//   -> per instruction, lanes 4c..4c+3 fully cover one 64-B cache line: 1 request/line.
// emb[3a+cb][h][w] = A[a][w] * Bc[cb][h] (exact rank-1 separation incl. gaussian mask);
// using sA[a][w]=emb[3a][0][w], sB[cb][h]=emb[cb][h][0] scales everything by
// emb[0][0][0] > 0, which cancels in the L2 normalization.
__global__ __launch_bounds__(512) void ese_kernel(
        const float* __restrict__ x,     // (B, 128, 8, 8)
        const float* __restrict__ emb,   // (9, 8, 8)
        float* __restrict__ out)         // (B, 1152)
{
    __shared__ float s_out[OUT_PER_B];
    __shared__ float s_red[8];

    const int b = blockIdx.x;
    const int t = threadIdx.x;
    const int c = t >> 2;            // channel 0..127
    const int s = t & 3;             // quarter 0..3
    const int wb = (s & 1) * 4;      // w-base: 0 or 4
    const int hb = s >> 1;           // h offset: h = 2k + hb

    // Per-lane constant slices of emb (24 dwords, L1-resident after first block).
    float sAv[3][4];
#pragma unroll
    for (int a = 0; a < 3; ++a)
#pragma unroll
        for (int q = 0; q < 4; ++q)
            sAv[a][q] = emb[(3 * a) * 64 + wb + q];
    float sBv[3][4];
#pragma unroll
    for (int cc = 0; cc < 3; ++cc)
#pragma unroll
        for (int k = 0; k < 4; ++k)
            sBv[cc][k] = emb[cc * 64 + (2 * k + hb) * 8];

    const float4* __restrict__ xp =
        reinterpret_cast<const float4*>(x + ((size_t)b * IN_DIMS + c) * 64);

    float4 v[4];
#pragma unroll
    for (int k = 0; k < 4; ++k) v[k] = xp[s + 4 * k];

    float acc[9];
#pragma unroll
    for (int j = 0; j < 9; ++j) acc[j] = 0.0f;

#pragma unroll
    for (int k = 0; k < 4; ++k) {
#pragma unroll
        for (int a = 0; a < 3; ++a) {
            const float u = v[k].x * sAv[a][0] + v[k].y * sAv[a][1]
                          + v[k].z * sAv[a][2] + v[k].w * sAv[a][3];
#pragma unroll
            for (int cc = 0; cc < 3; ++cc)
                acc[3 * a + cc] += u * sBv[cc][k];
        }
    }

    // Merge the 4 lanes of this channel (butterfly -> all 4 hold the full sum).
#pragma unroll
    for (int off = 1; off <= 2; off <<= 1)
#pragma unroll
        for (int j = 0; j < 9; ++j)
            acc[j] += __shfl_xor(acc[j], off, 64);

    // Sum of squares across the block: per-group ss is identical on the 4 lanes,
    // reduce across the 16 groups of the wave, then across the 8 waves via LDS.
    float ss = 0.0f;
#pragma unroll
    for (int j = 0; j < 9; ++j) ss += acc[j] * acc[j];
#pragma unroll
    for (int off = 4; off <= 32; off <<= 1)
        ss += __shfl_xor(ss, off, 64);
    const int lane = t & 63;
    const int wid = t >> 6;
    if (lane == 0) s_red[wid] = ss;
    __syncthreads();
    float total = 0.0f;
#pragma unroll
    for (int r = 0; r < 8; ++r) total += s_red[r];
    const float rn = 1.0f / sqrtf(total + 1e-10f);

    // Stage normalized outputs (one writer lane per channel), then coalesced store.
    if (s == 0) {
#pragma unroll
        for (int j = 0; j < 9; ++j) s_out[c * 9 + j] = acc[j] * rn;
    }
    __syncthreads();

    float* __restrict__ ob = out + (size_t)b * OUT_PER_B;
    for (int idx = t; idx < OUT_PER_B; idx += 512)
        ob[idx] = s_out[idx];
}

extern "C" void kernel_launch(void* const* d_in, const int* in_sizes, int n_in,
                              void* d_out, int out_size, void* d_ws, size_t ws_size,
                              hipStream_t stream) {
    const float* x   = (const float*)d_in[0];
    const float* emb = (const float*)d_in[1];
    float* out       = (float*)d_out;

    const int B = in_sizes[0] / (IN_DIMS * 64);   // 4096
    ese_kernel<<<B, 512, 0, stream>>>(x, emb, out);
}